// Round 10
// baseline (342.924 us; speedup 1.0000x reference)
//
#include <hip/hip_runtime.h>

typedef unsigned short u16;
typedef unsigned int u32;
typedef __attribute__((ext_vector_type(8))) short short8;  // 8 bf16 = 4 VGPR (MFMA A/B frag)
typedef __attribute__((ext_vector_type(4))) float f32x4;   // MFMA C/D frag

#define T_LEN 4096
#define BATCH 4
#define M_TOT (BATCH*T_LEN)   /* 16384 rows */
#define NCHUNK 64
#define CLEN 64               /* 4096/64 */

__device__ __forceinline__ u16 f2bf(float f){
  u32 u = __builtin_bit_cast(u32, f);
  u32 r = (u + 0x7FFFu + ((u >> 16) & 1u)) >> 16;   // RTN-even
  return (u16)r;
}
__device__ __forceinline__ float bf2f(u16 h){
  u32 u = ((u32)h) << 16; return __builtin_bit_cast(float, u);
}
__device__ __forceinline__ float sigmoid_(float v){ return 1.f/(1.f + __expf(-v)); }
__device__ __forceinline__ float tanh_pi_(float v){
  return 3.14159265358979323846f * (1.f - 2.f/(1.f + __expf(2.f*v)));
}

// ---------------- fp32 -> bf16 convert (vectorized x4) ----------------
__global__ __launch_bounds__(256) void cvt_bf16_k(const float* __restrict__ in,
                                                  u16* __restrict__ out, int n4){
  int g = blockIdx.x*256 + threadIdx.x;
  if (g >= n4) return;
  float4 v = reinterpret_cast<const float4*>(in)[g];
  reinterpret_cast<ushort4*>(out)[g] =
      make_ushort4(f2bf(v.x), f2bf(v.y), f2bf(v.z), f2bf(v.w));
}

// ======= 256x256 8-phase bf16 GEMM (r6 core) + NREP persistent bm-tiles =======
// C[M,N] = A[M,K] @ B[N,K]^T. 512 thr = 8 waves (2M x 4N), BK=64, LDS 128 KiB dyn.
// r10 change: grid = (M/256/NREP)*(N/256); each block runs NREP bm-tiles with the
// SAME bn sequentially (B-panel L2-hot for rep>=1; one dispatch round -> XCD
// affinity holds for all work). Rep hazards audited: final peel phase reads no
// LDS after its barrier; epilogue is register-only; rep+1 prologue VMCNT(6) also
// drains epilogue stores.
// Phases by C-quadrant (mh,nh) x full K=64, JIT reads consumed same phase:
//   P0/P4 (0,0): 12 reads + lgkmcnt(8) | P1/P5 (0,1): 4 | P2/P6 (1,0): 8 | P3/P7: 0
// Stage map (2 gload_lds/phase):
//   P0: A1,A3(t+1) | P1: A0,A2(t+2) | P2: B0,B1(t+2) | P3: B2,B3(t+2) + VMCNT(6)
//   P4: A1,A3(t+2) | P5: A0,A2(t+3) | P6: B0,B1(t+3) | P7: B2,B3(t+3) + VMCNT(6)
// LDS swizzle: byte ^= (row&7)<<4 on reads; inverse-swizzled GLOBAL src on stages.
#define BAR() __builtin_amdgcn_s_barrier()
#define VMCNT(n) asm volatile("s_waitcnt vmcnt(" #n ")" ::: "memory")
#define LGKM0() asm volatile("s_waitcnt lgkmcnt(0)" ::: "memory")
#define LGKM8() asm volatile("s_waitcnt lgkmcnt(8)" ::: "memory")
#define FEN() asm volatile("" ::: "memory")
#define PRIO1() __builtin_amdgcn_s_setprio(1)
#define PRIO0() __builtin_amdgcn_s_setprio(0)

#define STAGE(buf, ab, q, kt) do { \
  const u16* _s = ((ab) ? Bb : Ab) + (size_t)(q)*rowK64 + (size_t)(kt)*64; \
  __builtin_amdgcn_global_load_lds( \
    (const __attribute__((address_space(1))) void*)_s, \
    (__attribute__((address_space(3))) void*)(smem + (buf)*65536 + (ab)*32768 + (q)*8192 + stb), \
    16, 0, 0); \
} while(0)

#define LDA(base, m, kk) (*(const short8*)((base) + (m)*2048 + ((kk) ? csw1 : csw0)))
#define LDB(base, n, kk) (*(const short8*)((base) + (n)*2048 + ((kk) ? csw1 : csw0)))

#define RD_A(base, h) do { _Pragma("unroll") \
  for (int ml=0; ml<4; ml++){ \
    aF[ml*2+0] = LDA(base, 4*(h)+ml, 0); \
    aF[ml*2+1] = LDA(base, 4*(h)+ml, 1); } } while(0)

#define RD_B(base, h) do { _Pragma("unroll") \
  for (int nl=0; nl<2; nl++){ \
    bF[(h)*4+nl*2+0] = LDB(base, 2*(h)+nl, 0); \
    bF[(h)*4+nl*2+1] = LDB(base, 2*(h)+nl, 1); } } while(0)

#define MFMAQ(mh, nh) do { _Pragma("unroll") \
  for (int kk=0; kk<2; kk++) \
  _Pragma("unroll") \
  for (int ml=0; ml<4; ml++) \
  _Pragma("unroll") \
  for (int nl=0; nl<2; nl++) \
    acc[4*(mh)+ml][2*(nh)+nl] = __builtin_amdgcn_mfma_f32_16x16x32_bf16( \
      aF[ml*2+kk], bF[(nh)*4+nl*2+kk], acc[4*(mh)+ml][2*(nh)+nl], 0,0,0); \
} while(0)

// EPI 0: GEMM1 -> bf16 activated res (col<1024: pi*tanh, else sigmoid)
// EPI 1: GEMM2 -> bf16 silu(v + bias)
// EPI 2: GEMM3 -> bf16 v + bias (RMSNorm consumes bf16, writes fp32 out)
template<int EPI, int NREP>
__global__ __launch_bounds__(512, 2) void gemm8p(
    const u16* __restrict__ Ag, const u16* __restrict__ Bg,
    const float* __restrict__ bias, void* __restrict__ Cout,
    int M, int N, int K)
{
  extern __shared__ __attribute__((aligned(16))) char smem[];
  const int tid = threadIdx.x;
  const int wid = tid >> 6, lane = tid & 63;
  const int wr = wid >> 2, wc = wid & 3;        // wave -> 128x64 output subtile
  const int fr = lane & 15, fq = lane >> 4;

  // T1: bijective XCD swizzle (nwg % 8 == 0 for all our launches)
  const int nbn = N >> 8;
  const int nwg = gridDim.x;
  const int bid = blockIdx.x;
  const int swzb = (bid & 7) * (nwg >> 3) + (bid >> 3);
  const int bmq = swzb / nbn, bn = swzb - bmq * nbn;

  const size_t rowK64 = (size_t)64 * K;
  const u32 stb = (u32)(wid << 10);   // wave-uniform LDS staging base within quarter

  // swizzled ds_read addressing (row&7 == fr&7 since m*16 = 0 mod 8)
  const u32 csw0 = (u32)((fq*16)      ^ ((fr & 7) << 4));
  const u32 csw1 = (u32)((64 + fq*16) ^ ((fr & 7) << 4));
  const char* aB0 = smem +         (u32)(wr*128 + fr) * 128;
  const char* aB1 = aB0 + 65536;
  const char* bB0 = smem + 32768 + (u32)(wc*64  + fr) * 128;
  const char* bB1 = bB0 + 65536;

  const int NT = K >> 6;   // K-tiles (16 or 32)

  short8 aF[8];   // current quadrant-row A frags (m-half x 2kk)
  short8 bF[8];   // B frags, both n-halves x 2kk (live across the tile)

#pragma unroll
  for (int rep = 0; rep < NREP; ++rep){
    const int bm = bmq * NREP + rep;   // adjacent bm-tiles, same bn (B L2-hot)

    // staging: thread t covers LDS bytes qbase + t*16 (linear); global source is
    // inverse-swizzled: row = t>>3 (within quarter), chunk = (t&7) ^ ((t>>3)&7)
    const u16* Ab = Ag + ((size_t)bm*256 + (tid>>3)) * K + ((tid & 7) ^ ((tid >> 3) & 7)) * 8;
    const u16* Bb = Bg + ((size_t)bn*256 + (tid>>3)) * K + ((tid & 7) ^ ((tid >> 3) & 7)) * 8;

    f32x4 acc[8][4];
#pragma unroll
    for (int m=0;m<8;m++)
#pragma unroll
      for (int n=0;n<4;n++) acc[m][n] = f32x4{0.f,0.f,0.f,0.f};

    // prologue: tile0 all 8; tile1 A0,A2 + B all (6); gate retires tile0
    // (at rep>=1 the VMCNT also drains the previous epilogue's stores)
    STAGE(0,0,0,0); STAGE(0,0,1,0); STAGE(0,0,2,0); STAGE(0,0,3,0);
    STAGE(0,1,0,0); STAGE(0,1,1,0); STAGE(0,1,2,0); STAGE(0,1,3,0);
    STAGE(1,0,0,1); STAGE(1,0,2,1);
    STAGE(1,1,0,1); STAGE(1,1,1,1); STAGE(1,1,2,1); STAGE(1,1,3,1);
    VMCNT(6);
    BAR();

    for (int i = 0; i < (NT>>1) - 1; ++i){
      const int tt = 2*i;
      // P0 (buf0, quad 0,0): 12 reads + lgkm8 pace
      RD_A(aB0,0); RD_B(bB0,0); FEN();
      STAGE(1,0,1,tt+1); STAGE(1,0,3,tt+1);
      LGKM8();
      BAR(); LGKM0();
      PRIO1(); MFMAQ(0,0); PRIO0();
      BAR();
      // P1 (0,1): 4 reads
      RD_B(bB0,1); FEN();
      STAGE(0,0,0,tt+2); STAGE(0,0,2,tt+2);
      BAR(); LGKM0();
      PRIO1(); MFMAQ(0,1); PRIO0();
      BAR();
      // P2 (1,0): 8 reads
      RD_A(aB0,1); FEN();
      STAGE(0,1,0,tt+2); STAGE(0,1,1,tt+2);
      BAR(); LGKM0();
      PRIO1(); MFMAQ(1,0); PRIO0();
      BAR();
      // P3 (1,1): 0 reads; gate tile t+1
      STAGE(0,1,2,tt+2); STAGE(0,1,3,tt+2);
      BAR();
      PRIO1(); MFMAQ(1,1); PRIO0();
      VMCNT(6);
      BAR();
      // P4 (buf1, quad 0,0)
      RD_A(aB1,0); RD_B(bB1,0); FEN();
      STAGE(0,0,1,tt+2); STAGE(0,0,3,tt+2);
      LGKM8();
      BAR(); LGKM0();
      PRIO1(); MFMAQ(0,0); PRIO0();
      BAR();
      // P5 (0,1)
      RD_B(bB1,1); FEN();
      STAGE(1,0,0,tt+3); STAGE(1,0,2,tt+3);
      BAR(); LGKM0();
      PRIO1(); MFMAQ(0,1); PRIO0();
      BAR();
      // P6 (1,0)
      RD_A(aB1,1); FEN();
      STAGE(1,1,0,tt+3); STAGE(1,1,1,tt+3);
      BAR(); LGKM0();
      PRIO1(); MFMAQ(1,0); PRIO0();
      BAR();
      // P7 (1,1): gate tile t+2
      STAGE(1,1,2,tt+3); STAGE(1,1,3,tt+3);
      BAR();
      PRIO1(); MFMAQ(1,1); PRIO0();
      VMCNT(6);
      BAR();
    }
    { // peeled final iteration: tiles NT-2 (buf0), NT-1 (buf1)
      RD_A(aB0,0); RD_B(bB0,0); FEN();
      STAGE(1,0,1,NT-1); STAGE(1,0,3,NT-1);
      LGKM8();
      BAR(); LGKM0();
      PRIO1(); MFMAQ(0,0); PRIO0();
      BAR();
      RD_B(bB0,1); FEN();
      BAR(); LGKM0();
      PRIO1(); MFMAQ(0,1); PRIO0();
      BAR();
      RD_A(aB0,1); FEN();
      BAR(); LGKM0();
      PRIO1(); MFMAQ(1,0); PRIO0();
      BAR();
      BAR();
      PRIO1(); MFMAQ(1,1); PRIO0();
      VMCNT(0);     // drain: tile NT-1 fully landed
      BAR();
      RD_A(aB1,0); RD_B(bB1,0); FEN();
      BAR(); LGKM0();
      PRIO1(); MFMAQ(0,0); PRIO0();
      BAR();
      RD_B(bB1,1); FEN();
      BAR(); LGKM0();
      PRIO1(); MFMAQ(0,1); PRIO0();
      BAR();
      RD_A(aB1,1); FEN();
      BAR(); LGKM0();
      PRIO1(); MFMAQ(1,0); PRIO0();
      BAR();
      PRIO1(); MFMAQ(1,1); PRIO0();
    }

    // epilogue: D reg r -> row = fq*4 + r, col = fr (m89-verified mapping)
    const int orow0 = bm*256 + wr*128;
    const int ocol0 = bn*256 + wc*64;
#pragma unroll
    for (int m=0;m<8;m++){
#pragma unroll
      for (int n=0;n<4;n++){
        const int col = ocol0 + n*16 + fr;
#pragma unroll
        for (int r=0;r<4;r++){
          const int row = orow0 + m*16 + fq*4 + r;
          float v = acc[m][n][r];
          if constexpr (EPI == 0){
            float o = (col < 1024) ? tanh_pi_(v) : sigmoid_(v);
            ((u16*)Cout)[(size_t)row*N + col] = f2bf(o);
          } else if constexpr (EPI == 1){
            v += bias[col];
            ((u16*)Cout)[(size_t)row*N + col] = f2bf(v * sigmoid_(v));
          } else {
            v += bias[col];
            ((u16*)Cout)[(size_t)row*N + col] = f2bf(v);
          }
        }
      }
    }
    if (rep + 1 < NREP) BAR();   // all waves' LDS reads done before next prologue
  }
}

// ---------------- chunked lerp scan (res bf16, 2 channels/thread) ----------------
// res layout: [b][t][2048] bf16, col<1024 = theta' (pi*tanh), col>=1024 = s.
// recurrence: h_t = (1-s_t) h_{t-1} + s_t * theta'_t, h_{-1} = 0 (fp32 state)
__global__ __launch_bounds__(256) void scan_stage1(const u16* __restrict__ res,
                                                   float* __restrict__ sA,
                                                   float* __restrict__ sB,
                                                   float* __restrict__ sA2,
                                                   float* __restrict__ sB2){
  const int c0    = ((blockIdx.x & 1)*256 + threadIdx.x)*2;
  const int chunk = (blockIdx.x >> 1) & (NCHUNK-1);
  const int b     = blockIdx.x >> 7;
  const u16* p = res + ((size_t)(b*T_LEN + chunk*CLEN))*2048 + c0;
  float A0=1.f, B0v=0.f, A1=1.f, B1v=0.f;
#pragma unroll 4
  for (int t=0;t<CLEN-1;++t){
    ushort2 th = *reinterpret_cast<const ushort2*>(p);
    ushort2 sg = *reinterpret_cast<const ushort2*>(p+1024);
    float s0 = bf2f(sg.x), s1 = bf2f(sg.y);
    float a0 = 1.f - s0,   a1 = 1.f - s1;
    A0 *= a0;  B0v = a0*B0v + s0*bf2f(th.x);
    A1 *= a1;  B1v = a1*B1v + s1*bf2f(th.y);
    p += 2048;
  }
  const int idx = (b*NCHUNK + chunk)*1024 + c0;
  *reinterpret_cast<float2*>(&sA2[idx]) = make_float2(A0, A1);
  *reinterpret_cast<float2*>(&sB2[idx]) = make_float2(B0v, B1v);
  {
    ushort2 th = *reinterpret_cast<const ushort2*>(p);
    ushort2 sg = *reinterpret_cast<const ushort2*>(p+1024);
    float s0 = bf2f(sg.x), s1 = bf2f(sg.y);
    float a0 = 1.f - s0,   a1 = 1.f - s1;
    A0 *= a0;  B0v = a0*B0v + s0*bf2f(th.x);
    A1 *= a1;  B1v = a1*B1v + s1*bf2f(th.y);
  }
  *reinterpret_cast<float2*>(&sA[idx]) = make_float2(A0, A1);
  *reinterpret_cast<float2*>(&sB[idx]) = make_float2(B0v, B1v);
}

__global__ __launch_bounds__(256) void scan_stage2(const float* __restrict__ sA,
                                                   const float* __restrict__ sB,
                                                   float* __restrict__ Hp){
  const int g = blockIdx.x*256 + threadIdx.x;   // 4096 threads: b*1024+c
  const int b = g >> 10, c = g & 1023;
  float H = 0.f;
#pragma unroll
  for (int i=0;i<NCHUNK;++i){
    const int idx = (b*NCHUNK + i)*1024 + c;
    Hp[idx] = H;                 // state BEFORE chunk i
    H = sA[idx]*H + sB[idx];
  }
}

// ------- fused stage3 + depthwise causal conv(3) -> bf16 z (2 channels/thread) -------
__global__ __launch_bounds__(256) void scan3_conv_k(const u16* __restrict__ res,
                                                    const float* __restrict__ Hp,
                                                    const float* __restrict__ sA2,
                                                    const float* __restrict__ sB2,
                                                    const float* __restrict__ cw,
                                                    const float* __restrict__ cb,
                                                    u16* __restrict__ z){
  const int c0    = ((blockIdx.x & 1)*256 + threadIdx.x)*2;
  const int chunk = (blockIdx.x >> 1) & (NCHUNK-1);
  const int b     = blockIdx.x >> 7;
  const u16* p = res + ((size_t)(b*T_LEN + chunk*CLEN))*2048 + c0;
  u16*       q = z   + ((size_t)(b*T_LEN + chunk*CLEN))*1024 + c0;
  const int idx = (b*NCHUNK + chunk)*1024 + c0;
  float H0 = Hp[idx], H1 = Hp[idx+1];          // h[t0-1] (0 for chunk 0)
  float hm1_0 = H0, hm1_1 = H1;
  float hm2_0 = 0.f, hm2_1 = 0.f;
  if (chunk > 0){
    const int pidx = idx - 1024;
    hm2_0 = sA2[pidx]*Hp[pidx] + sB2[pidx];        // h[t0-2]
    hm2_1 = sA2[pidx+1]*Hp[pidx+1] + sB2[pidx+1];
  }
  const float w0_0 = cw[3*c0],   w1_0 = cw[3*c0+1], w2_0 = cw[3*c0+2], bb0 = cb[c0];
  const float w0_1 = cw[3*c0+3], w1_1 = cw[3*c0+4], w2_1 = cw[3*c0+5], bb1 = cb[c0+1];
#pragma unroll 4
  for (int t=0;t<CLEN;++t){
    ushort2 th = *reinterpret_cast<const ushort2*>(p);
    ushort2 sg = *reinterpret_cast<const ushort2*>(p+1024);
    float s0 = bf2f(sg.x), s1 = bf2f(sg.y);
    H0 = (1.f - s0)*H0 + s0*bf2f(th.x);
    H1 = (1.f - s1)*H1 + s1*bf2f(th.y);
    float v0 = H0 + bb0 + hm2_0*w0_0 + hm1_0*w1_0 + H0*w2_0;
    float v1 = H1 + bb1 + hm2_1*w0_1 + hm1_1*w1_1 + H1*w2_1;
    *reinterpret_cast<ushort2*>(q) = make_ushort2(f2bf(v0), f2bf(v1));
    hm2_0 = hm1_0; hm1_0 = H0;
    hm2_1 = hm1_1; hm1_1 = H1;
    p += 2048; q += 1024;
  }
}

// ------- row RMSNorm: bf16 in (h_final+bias), fp32 out; one block per row -------
__global__ __launch_bounds__(256) void rmsnorm_bf_k(const u16* __restrict__ in,
                                                    float* __restrict__ out,
                                                    const float* __restrict__ w){
  const int row = blockIdx.x;
  const int tid = threadIdx.x;
  const u16* p = in + (size_t)row*1024 + tid*4;
  ushort4 v4 = *reinterpret_cast<const ushort4*>(p);
  float a = bf2f(v4.x), b = bf2f(v4.y), c = bf2f(v4.z), d = bf2f(v4.w);
  float ss = a*a + b*b + c*c + d*d;
#pragma unroll
  for (int o=32; o>0; o>>=1) ss += __shfl_xor(ss, o, 64);
  __shared__ float red[4];
  if ((tid & 63) == 0) red[tid >> 6] = ss;
  __syncthreads();
  float tot = red[0] + red[1] + red[2] + red[3];
  float scale = rsqrtf(tot * (1.f/1024.f) + 1e-6f);
  float4 wv = reinterpret_cast<const float4*>(w)[tid];
  float4 o;
  o.x = a*scale*wv.x; o.y = b*scale*wv.y;
  o.z = c*scale*wv.z; o.w = d*scale*wv.w;
  reinterpret_cast<float4*>(out + (size_t)row*1024)[tid] = o;
}

extern "C" void kernel_launch(void* const* d_in, const int* in_sizes, int n_in,
                              void* d_out, int out_size, void* d_ws, size_t ws_size,
                              hipStream_t stream) {
  const float* x      = (const float*)d_in[0];
  const float* w_key  = (const float*)d_in[1];
  const float* conv_w = (const float*)d_in[2];
  const float* conv_b = (const float*)d_in[3];
  const float* w1     = (const float*)d_in[4];
  const float* b1     = (const float*)d_in[5];
  const float* w2     = (const float*)d_in[6];
  const float* b2     = (const float*)d_in[7];
  const float* norm_w = (const float*)d_in[8];
  float* out = (float*)d_out;
  char*  ws  = (char*)d_ws;

  // workspace layout (~120 MB)
  size_t off = 0;
  u16*   RES  = (u16*)  (ws + off); off += (size_t)M_TOT*2048*2; // bf16 res; reused as hid
  u16*   XB   = (u16*)  (ws + off); off += (size_t)M_TOT*1024*2; // x bf16; reused as z, then h_final
  u16*   WK   = (u16*)  (ws + off); off += (size_t)2048*1024*2;
  u16*   W1B  = (u16*)  (ws + off); off += (size_t)2048*1024*2;
  u16*   W2B  = (u16*)  (ws + off); off += (size_t)1024*2048*2;
  float* SA   = (float*)(ws + off); off += (size_t)BATCH*NCHUNK*1024*4;
  float* SB   = (float*)(ws + off); off += (size_t)BATCH*NCHUNK*1024*4;
  float* SA2  = (float*)(ws + off); off += (size_t)BATCH*NCHUNK*1024*4;
  float* SB2  = (float*)(ws + off); off += (size_t)BATCH*NCHUNK*1024*4;
  float* HP   = (float*)(ws + off); off += (size_t)BATCH*NCHUNK*1024*4;
  u16* ZB  = XB;   // z aliases x_bf16 (dead after GEMM1)
  u16* HID = RES;  // hid aliases res (dead after scan3_conv_k)
  u16* HF  = XB;   // GEMM3 bf16 output aliases z (dead after GEMM2)

  // allow 128 KiB dynamic LDS (idempotent host-side calls, graph-capture safe)
  hipFuncSetAttribute((const void*)gemm8p<0,2>, hipFuncAttributeMaxDynamicSharedMemorySize, 131072);
  hipFuncSetAttribute((const void*)gemm8p<1,2>, hipFuncAttributeMaxDynamicSharedMemorySize, 131072);
  hipFuncSetAttribute((const void*)gemm8p<2,1>, hipFuncAttributeMaxDynamicSharedMemorySize, 131072);

  // 1) fp32 -> bf16 converts
  cvt_bf16_k<<<(M_TOT*1024/4 + 255)/256, 256, 0, stream>>>(x,     XB,  M_TOT*1024/4);
  cvt_bf16_k<<<(2048*1024/4  + 255)/256, 256, 0, stream>>>(w_key, WK,  2048*1024/4);
  cvt_bf16_k<<<(2048*1024/4  + 255)/256, 256, 0, stream>>>(w1,    W1B, 2048*1024/4);
  cvt_bf16_k<<<(1024*2048/4  + 255)/256, 256, 0, stream>>>(w2,    W2B, 1024*2048/4);

  // 2) GEMM1 + activation epilogue -> res (bf16); 256 blocks x 2 bm-reps
  gemm8p<0,2><<<(M_TOT/512)*(2048/256), 512, 131072, stream>>>(XB, WK, nullptr, RES, M_TOT, 2048, 1024);

  // 3) chunked scan; stage3 fused with depthwise conv -> z (bf16)
  scan_stage1<<<BATCH*NCHUNK*2, 256, 0, stream>>>(RES, SA, SB, SA2, SB2);
  scan_stage2<<<16, 256, 0, stream>>>(SA, SB, HP);
  scan3_conv_k<<<BATCH*NCHUNK*2, 256, 0, stream>>>(RES, HP, SA2, SB2, conv_w, conv_b, ZB);

  // 5) GEMM2 + silu -> hid (bf16); 256 blocks x 2 bm-reps
  gemm8p<1,2><<<(M_TOT/512)*(2048/256), 512, 131072, stream>>>(ZB, W1B, b1, HID, M_TOT, 2048, 1024);

  // 6) GEMM3 + bias -> h_final (bf16, into dead z buffer); 256 blocks x 1
  gemm8p<2,1><<<(M_TOT/256)*(1024/256), 512, 131072, stream>>>(HID, W2B, b2, HF, M_TOT, 1024, 2048);

  // 7) RMSNorm: bf16 in -> fp32 out
  rmsnorm_bf_k<<<M_TOT, 256, 0, stream>>>(HF, out, norm_w);
}

// Round 11
// 317.793 us; speedup vs baseline: 1.0791x; 1.0791x over previous
//
#include <hip/hip_runtime.h>

typedef unsigned short u16;
typedef unsigned int u32;
typedef __attribute__((ext_vector_type(8))) short short8;  // 8 bf16 = 4 VGPR (MFMA A/B frag)
typedef __attribute__((ext_vector_type(4))) float f32x4;   // MFMA C/D frag

#define T_LEN 4096
#define BATCH 4
#define M_TOT (BATCH*T_LEN)   /* 16384 rows */
#define NCHUNK 64
#define CLEN 64               /* 4096/64 */

__device__ __forceinline__ u16 f2bf(float f){
  u32 u = __builtin_bit_cast(u32, f);
  u32 r = (u + 0x7FFFu + ((u >> 16) & 1u)) >> 16;   // RTN-even
  return (u16)r;
}
__device__ __forceinline__ float bf2f(u16 h){
  u32 u = ((u32)h) << 16; return __builtin_bit_cast(float, u);
}
__device__ __forceinline__ float sigmoid_(float v){ return 1.f/(1.f + __expf(-v)); }
__device__ __forceinline__ float tanh_pi_(float v){
  return 3.14159265358979323846f * (1.f - 2.f/(1.f + __expf(2.f*v)));
}

// ---------------- fp32 -> bf16 convert (vectorized x4) ----------------
__global__ __launch_bounds__(256) void cvt_bf16_k(const float* __restrict__ in,
                                                  u16* __restrict__ out, int n4){
  int g = blockIdx.x*256 + threadIdx.x;
  if (g >= n4) return;
  float4 v = reinterpret_cast<const float4*>(in)[g];
  reinterpret_cast<ushort4*>(out)[g] =
      make_ushort4(f2bf(v.x), f2bf(v.y), f2bf(v.z), f2bf(v.w));
}

// ---- w_key convert with ROW PERMUTE: row e -> (e<1024 ? 2e : 2(e-1024)+1) ----
// Makes GEMM1's res columns interleave as [theta_0, s_0, theta_1, s_1, ...] so the
// scan kernels read each channel's (theta,s) pair as one ushort4.
__global__ __launch_bounds__(256) void cvt_wkey_perm_k(const float* __restrict__ in,
                                                       u16* __restrict__ out){
  int g = blockIdx.x*256 + threadIdx.x;          // g indexes float4 over 2048x1024
  const int row  = g >> 8;                       // 256 float4 per 1024-col row
  const int col4 = g & 255;
  const int prow = (row < 1024) ? (2*row) : (2*(row-1024)+1);
  float4 v = reinterpret_cast<const float4*>(in)[g];
  reinterpret_cast<ushort4*>(out)[prow*256 + col4] =
      make_ushort4(f2bf(v.x), f2bf(v.y), f2bf(v.z), f2bf(v.w));
}

// ======= 256x256 8-phase bf16 GEMM (r6/r9 known-good core, NREP reverted) =======
// C[M,N] = A[M,K] @ B[N,K]^T. 512 thr = 8 waves (2M x 4N), BK=64, LDS 128 KiB dyn.
// Phases by C-quadrant (mh,nh) x full K=64, JIT reads consumed same phase:
//   P0/P4 (0,0): 12 reads + lgkmcnt(8) | P1/P5 (0,1): 4 | P2/P6 (1,0): 8 | P3/P7: 0
// Stage map (2 gload_lds/phase):
//   P0: A1,A3(t+1) | P1: A0,A2(t+2) | P2: B0,B1(t+2) | P3: B2,B3(t+2) + VMCNT(6)
//   P4: A1,A3(t+2) | P5: A0,A2(t+3) | P6: B0,B1(t+3) | P7: B2,B3(t+3) + VMCNT(6)
// LDS swizzle: byte ^= (row&7)<<4 on reads; inverse-swizzled GLOBAL src on stages.
#define BAR() __builtin_amdgcn_s_barrier()
#define VMCNT(n) asm volatile("s_waitcnt vmcnt(" #n ")" ::: "memory")
#define LGKM0() asm volatile("s_waitcnt lgkmcnt(0)" ::: "memory")
#define LGKM8() asm volatile("s_waitcnt lgkmcnt(8)" ::: "memory")
#define FEN() asm volatile("" ::: "memory")
#define PRIO1() __builtin_amdgcn_s_setprio(1)
#define PRIO0() __builtin_amdgcn_s_setprio(0)

#define STAGE(buf, ab, q, kt) do { \
  const u16* _s = ((ab) ? Bb : Ab) + (size_t)(q)*rowK64 + (size_t)(kt)*64; \
  __builtin_amdgcn_global_load_lds( \
    (const __attribute__((address_space(1))) void*)_s, \
    (__attribute__((address_space(3))) void*)(smem + (buf)*65536 + (ab)*32768 + (q)*8192 + stb), \
    16, 0, 0); \
} while(0)

#define LDA(base, m, kk) (*(const short8*)((base) + (m)*2048 + ((kk) ? csw1 : csw0)))
#define LDB(base, n, kk) (*(const short8*)((base) + (n)*2048 + ((kk) ? csw1 : csw0)))

#define RD_A(base, h) do { _Pragma("unroll") \
  for (int ml=0; ml<4; ml++){ \
    aF[ml*2+0] = LDA(base, 4*(h)+ml, 0); \
    aF[ml*2+1] = LDA(base, 4*(h)+ml, 1); } } while(0)

#define RD_B(base, h) do { _Pragma("unroll") \
  for (int nl=0; nl<2; nl++){ \
    bF[(h)*4+nl*2+0] = LDB(base, 2*(h)+nl, 0); \
    bF[(h)*4+nl*2+1] = LDB(base, 2*(h)+nl, 1); } } while(0)

#define MFMAQ(mh, nh) do { _Pragma("unroll") \
  for (int kk=0; kk<2; kk++) \
  _Pragma("unroll") \
  for (int ml=0; ml<4; ml++) \
  _Pragma("unroll") \
  for (int nl=0; nl<2; nl++) \
    acc[4*(mh)+ml][2*(nh)+nl] = __builtin_amdgcn_mfma_f32_16x16x32_bf16( \
      aF[ml*2+kk], bF[(nh)*4+nl*2+kk], acc[4*(mh)+ml][2*(nh)+nl], 0,0,0); \
} while(0)

// EPI 0: GEMM1 -> bf16 activated res, INTERLEAVED cols (even: pi*tanh, odd: sigmoid)
// EPI 1: GEMM2 -> bf16 silu(v + bias)
// EPI 2: GEMM3 -> bf16 v + bias (RMSNorm consumes bf16, writes fp32 out)
template<int EPI>
__global__ __launch_bounds__(512, 2) void gemm8p(
    const u16* __restrict__ Ag, const u16* __restrict__ Bg,
    const float* __restrict__ bias, void* __restrict__ Cout,
    int M, int N, int K)
{
  extern __shared__ __attribute__((aligned(16))) char smem[];
  const int tid = threadIdx.x;
  const int wid = tid >> 6, lane = tid & 63;
  const int wr = wid >> 2, wc = wid & 3;        // wave -> 128x64 output subtile
  const int fr = lane & 15, fq = lane >> 4;

  // T1: bijective XCD swizzle (nwg % 8 == 0 for all our launches)
  const int nbn = N >> 8;
  const int nwg = gridDim.x;
  const int bid = blockIdx.x;
  const int swzb = (bid & 7) * (nwg >> 3) + (bid >> 3);
  const int bm = swzb / nbn, bn = swzb - bm * nbn;

  const size_t rowK64 = (size_t)64 * K;
  // staging: thread t covers LDS bytes qbase + t*16 (linear); global source is
  // inverse-swizzled: row = t>>3 (within quarter), chunk = (t&7) ^ ((t>>3)&7)
  const u16* Ab = Ag + ((size_t)bm*256 + (tid>>3)) * K + ((tid & 7) ^ ((tid >> 3) & 7)) * 8;
  const u16* Bb = Bg + ((size_t)bn*256 + (tid>>3)) * K + ((tid & 7) ^ ((tid >> 3) & 7)) * 8;
  const u32 stb = (u32)(wid << 10);   // wave-uniform LDS staging base within quarter

  // swizzled ds_read addressing (row&7 == fr&7 since m*16 = 0 mod 8)
  const u32 csw0 = (u32)((fq*16)      ^ ((fr & 7) << 4));
  const u32 csw1 = (u32)((64 + fq*16) ^ ((fr & 7) << 4));
  const char* aB0 = smem +         (u32)(wr*128 + fr) * 128;
  const char* aB1 = aB0 + 65536;
  const char* bB0 = smem + 32768 + (u32)(wc*64  + fr) * 128;
  const char* bB1 = bB0 + 65536;

  f32x4 acc[8][4];
#pragma unroll
  for (int m=0;m<8;m++)
#pragma unroll
    for (int n=0;n<4;n++) acc[m][n] = f32x4{0.f,0.f,0.f,0.f};

  short8 aF[8];   // current quadrant-row A frags (m-half x 2kk)
  short8 bF[8];   // B frags, both n-halves x 2kk (live across the tile)

  const int NT = K >> 6;   // K-tiles (16 or 32)

  // prologue: tile0 all 8; tile1 A0,A2 + B all (6); gate retires tile0
  STAGE(0,0,0,0); STAGE(0,0,1,0); STAGE(0,0,2,0); STAGE(0,0,3,0);
  STAGE(0,1,0,0); STAGE(0,1,1,0); STAGE(0,1,2,0); STAGE(0,1,3,0);
  STAGE(1,0,0,1); STAGE(1,0,2,1);
  STAGE(1,1,0,1); STAGE(1,1,1,1); STAGE(1,1,2,1); STAGE(1,1,3,1);
  VMCNT(6);
  BAR();

  for (int i = 0; i < (NT>>1) - 1; ++i){
    const int tt = 2*i;
    // P0 (buf0, quad 0,0): 12 reads + lgkm8 pace
    RD_A(aB0,0); RD_B(bB0,0); FEN();
    STAGE(1,0,1,tt+1); STAGE(1,0,3,tt+1);
    LGKM8();
    BAR(); LGKM0();
    PRIO1(); MFMAQ(0,0); PRIO0();
    BAR();
    // P1 (0,1): 4 reads
    RD_B(bB0,1); FEN();
    STAGE(0,0,0,tt+2); STAGE(0,0,2,tt+2);
    BAR(); LGKM0();
    PRIO1(); MFMAQ(0,1); PRIO0();
    BAR();
    // P2 (1,0): 8 reads
    RD_A(aB0,1); FEN();
    STAGE(0,1,0,tt+2); STAGE(0,1,1,tt+2);
    BAR(); LGKM0();
    PRIO1(); MFMAQ(1,0); PRIO0();
    BAR();
    // P3 (1,1): 0 reads; gate tile t+1
    STAGE(0,1,2,tt+2); STAGE(0,1,3,tt+2);
    BAR();
    PRIO1(); MFMAQ(1,1); PRIO0();
    VMCNT(6);
    BAR();
    // P4 (buf1, quad 0,0)
    RD_A(aB1,0); RD_B(bB1,0); FEN();
    STAGE(0,0,1,tt+2); STAGE(0,0,3,tt+2);
    LGKM8();
    BAR(); LGKM0();
    PRIO1(); MFMAQ(0,0); PRIO0();
    BAR();
    // P5 (0,1)
    RD_B(bB1,1); FEN();
    STAGE(1,0,0,tt+3); STAGE(1,0,2,tt+3);
    BAR(); LGKM0();
    PRIO1(); MFMAQ(0,1); PRIO0();
    BAR();
    // P6 (1,0)
    RD_A(aB1,1); FEN();
    STAGE(1,1,0,tt+3); STAGE(1,1,1,tt+3);
    BAR(); LGKM0();
    PRIO1(); MFMAQ(1,0); PRIO0();
    BAR();
    // P7 (1,1): gate tile t+2
    STAGE(1,1,2,tt+3); STAGE(1,1,3,tt+3);
    BAR();
    PRIO1(); MFMAQ(1,1); PRIO0();
    VMCNT(6);
    BAR();
  }
  { // peeled final iteration: tiles NT-2 (buf0), NT-1 (buf1)
    RD_A(aB0,0); RD_B(bB0,0); FEN();
    STAGE(1,0,1,NT-1); STAGE(1,0,3,NT-1);
    LGKM8();
    BAR(); LGKM0();
    PRIO1(); MFMAQ(0,0); PRIO0();
    BAR();
    RD_B(bB0,1); FEN();
    BAR(); LGKM0();
    PRIO1(); MFMAQ(0,1); PRIO0();
    BAR();
    RD_A(aB0,1); FEN();
    BAR(); LGKM0();
    PRIO1(); MFMAQ(1,0); PRIO0();
    BAR();
    BAR();
    PRIO1(); MFMAQ(1,1); PRIO0();
    VMCNT(0);     // drain: tile NT-1 fully landed
    BAR();
    RD_A(aB1,0); RD_B(bB1,0); FEN();
    BAR(); LGKM0();
    PRIO1(); MFMAQ(0,0); PRIO0();
    BAR();
    RD_B(bB1,1); FEN();
    BAR(); LGKM0();
    PRIO1(); MFMAQ(0,1); PRIO0();
    BAR();
    RD_A(aB1,1); FEN();
    BAR(); LGKM0();
    PRIO1(); MFMAQ(1,0); PRIO0();
    BAR();
    PRIO1(); MFMAQ(1,1); PRIO0();
  }

  // epilogue: D reg r -> row = fq*4 + r, col = fr (m89-verified mapping)
  const int orow0 = bm*256 + wr*128;
  const int ocol0 = bn*256 + wc*64;
#pragma unroll
  for (int m=0;m<8;m++){
#pragma unroll
    for (int n=0;n<4;n++){
      const int col = ocol0 + n*16 + fr;
#pragma unroll
      for (int r=0;r<4;r++){
        const int row = orow0 + m*16 + fq*4 + r;
        float v = acc[m][n][r];
        if constexpr (EPI == 0){
          // interleaved res: even col = theta channel, odd col = gate channel
          float o = ((col & 1) == 0) ? tanh_pi_(v) : sigmoid_(v);
          ((u16*)Cout)[(size_t)row*N + col] = f2bf(o);
        } else if constexpr (EPI == 1){
          v += bias[col];
          ((u16*)Cout)[(size_t)row*N + col] = f2bf(v * sigmoid_(v));
        } else {
          v += bias[col];
          ((u16*)Cout)[(size_t)row*N + col] = f2bf(v);
        }
      }
    }
  }
}

// ---------------- chunked lerp scan (res bf16 INTERLEAVED, 2 channels/thread) ----------------
// res layout: [b][t][2048] bf16, col 2c = theta'_c (pi*tanh), col 2c+1 = s_c.
// recurrence: h_t = (1-s_t) h_{t-1} + s_t * theta'_t, h_{-1} = 0 (fp32 state)
__global__ __launch_bounds__(256) void scan_stage1(const u16* __restrict__ res,
                                                   float* __restrict__ sA,
                                                   float* __restrict__ sB,
                                                   float* __restrict__ sA2,
                                                   float* __restrict__ sB2){
  const int c0    = ((blockIdx.x & 1)*256 + threadIdx.x)*2;   // first channel
  const int chunk = (blockIdx.x >> 1) & (NCHUNK-1);
  const int b     = blockIdx.x >> 7;
  const u16* p = res + ((size_t)(b*T_LEN + chunk*CLEN))*2048 + 2*c0;
  float A0=1.f, B0v=0.f, A1=1.f, B1v=0.f;
#pragma unroll 4
  for (int t=0;t<CLEN-1;++t){
    ushort4 v = *reinterpret_cast<const ushort4*>(p);
    float s0 = bf2f(v.y), s1 = bf2f(v.w);
    float a0 = 1.f - s0,  a1 = 1.f - s1;
    A0 *= a0;  B0v = a0*B0v + s0*bf2f(v.x);
    A1 *= a1;  B1v = a1*B1v + s1*bf2f(v.z);
    p += 2048;
  }
  const int idx = (b*NCHUNK + chunk)*1024 + c0;
  *reinterpret_cast<float2*>(&sA2[idx]) = make_float2(A0, A1);
  *reinterpret_cast<float2*>(&sB2[idx]) = make_float2(B0v, B1v);
  {
    ushort4 v = *reinterpret_cast<const ushort4*>(p);
    float s0 = bf2f(v.y), s1 = bf2f(v.w);
    float a0 = 1.f - s0,  a1 = 1.f - s1;
    A0 *= a0;  B0v = a0*B0v + s0*bf2f(v.x);
    A1 *= a1;  B1v = a1*B1v + s1*bf2f(v.z);
  }
  *reinterpret_cast<float2*>(&sA[idx]) = make_float2(A0, A1);
  *reinterpret_cast<float2*>(&sB[idx]) = make_float2(B0v, B1v);
}

__global__ __launch_bounds__(256) void scan_stage2(const float* __restrict__ sA,
                                                   const float* __restrict__ sB,
                                                   float* __restrict__ Hp){
  const int g = blockIdx.x*256 + threadIdx.x;   // 4096 threads: b*1024+c
  const int b = g >> 10, c = g & 1023;
  float H = 0.f;
#pragma unroll
  for (int i=0;i<NCHUNK;++i){
    const int idx = (b*NCHUNK + i)*1024 + c;
    Hp[idx] = H;                 // state BEFORE chunk i
    H = sA[idx]*H + sB[idx];
  }
}

// ------- fused stage3 + depthwise causal conv(3) -> bf16 z (2 channels/thread) -------
__global__ __launch_bounds__(256) void scan3_conv_k(const u16* __restrict__ res,
                                                    const float* __restrict__ Hp,
                                                    const float* __restrict__ sA2,
                                                    const float* __restrict__ sB2,
                                                    const float* __restrict__ cw,
                                                    const float* __restrict__ cb,
                                                    u16* __restrict__ z){
  const int c0    = ((blockIdx.x & 1)*256 + threadIdx.x)*2;
  const int chunk = (blockIdx.x >> 1) & (NCHUNK-1);
  const int b     = blockIdx.x >> 7;
  const u16* p = res + ((size_t)(b*T_LEN + chunk*CLEN))*2048 + 2*c0;
  u16*       q = z   + ((size_t)(b*T_LEN + chunk*CLEN))*1024 + c0;
  const int idx = (b*NCHUNK + chunk)*1024 + c0;
  float H0 = Hp[idx], H1 = Hp[idx+1];          // h[t0-1] (0 for chunk 0)
  float hm1_0 = H0, hm1_1 = H1;
  float hm2_0 = 0.f, hm2_1 = 0.f;
  if (chunk > 0){
    const int pidx = idx - 1024;
    hm2_0 = sA2[pidx]*Hp[pidx] + sB2[pidx];        // h[t0-2]
    hm2_1 = sA2[pidx+1]*Hp[pidx+1] + sB2[pidx+1];
  }
  const float w0_0 = cw[3*c0],   w1_0 = cw[3*c0+1], w2_0 = cw[3*c0+2], bb0 = cb[c0];
  const float w0_1 = cw[3*c0+3], w1_1 = cw[3*c0+4], w2_1 = cw[3*c0+5], bb1 = cb[c0+1];
#pragma unroll 4
  for (int t=0;t<CLEN;++t){
    ushort4 v = *reinterpret_cast<const ushort4*>(p);
    float s0 = bf2f(v.y), s1 = bf2f(v.w);
    H0 = (1.f - s0)*H0 + s0*bf2f(v.x);
    H1 = (1.f - s1)*H1 + s1*bf2f(v.z);
    float o0 = H0 + bb0 + hm2_0*w0_0 + hm1_0*w1_0 + H0*w2_0;
    float o1 = H1 + bb1 + hm2_1*w0_1 + hm1_1*w1_1 + H1*w2_1;
    *reinterpret_cast<ushort2*>(q) = make_ushort2(f2bf(o0), f2bf(o1));
    hm2_0 = hm1_0; hm1_0 = H0;
    hm2_1 = hm1_1; hm1_1 = H1;
    p += 2048; q += 1024;
  }
}

// ------- row RMSNorm: bf16 in (h_final+bias), fp32 out; one block per row -------
__global__ __launch_bounds__(256) void rmsnorm_bf_k(const u16* __restrict__ in,
                                                    float* __restrict__ out,
                                                    const float* __restrict__ w){
  const int row = blockIdx.x;
  const int tid = threadIdx.x;
  const u16* p = in + (size_t)row*1024 + tid*4;
  ushort4 v4 = *reinterpret_cast<const ushort4*>(p);
  float a = bf2f(v4.x), b = bf2f(v4.y), c = bf2f(v4.z), d = bf2f(v4.w);
  float ss = a*a + b*b + c*c + d*d;
#pragma unroll
  for (int o=32; o>0; o>>=1) ss += __shfl_xor(ss, o, 64);
  __shared__ float red[4];
  if ((tid & 63) == 0) red[tid >> 6] = ss;
  __syncthreads();
  float tot = red[0] + red[1] + red[2] + red[3];
  float scale = rsqrtf(tot * (1.f/1024.f) + 1e-6f);
  float4 wv = reinterpret_cast<const float4*>(w)[tid];
  float4 o;
  o.x = a*scale*wv.x; o.y = b*scale*wv.y;
  o.z = c*scale*wv.z; o.w = d*scale*wv.w;
  reinterpret_cast<float4*>(out + (size_t)row*1024)[tid] = o;
}

extern "C" void kernel_launch(void* const* d_in, const int* in_sizes, int n_in,
                              void* d_out, int out_size, void* d_ws, size_t ws_size,
                              hipStream_t stream) {
  const float* x      = (const float*)d_in[0];
  const float* w_key  = (const float*)d_in[1];
  const float* conv_w = (const float*)d_in[2];
  const float* conv_b = (const float*)d_in[3];
  const float* w1     = (const float*)d_in[4];
  const float* b1     = (const float*)d_in[5];
  const float* w2     = (const float*)d_in[6];
  const float* b2     = (const float*)d_in[7];
  const float* norm_w = (const float*)d_in[8];
  float* out = (float*)d_out;
  char*  ws  = (char*)d_ws;

  // workspace layout (~120 MB)
  size_t off = 0;
  u16*   RES  = (u16*)  (ws + off); off += (size_t)M_TOT*2048*2; // bf16 res; reused as hid
  u16*   XB   = (u16*)  (ws + off); off += (size_t)M_TOT*1024*2; // x bf16; reused as z, then h_final
  u16*   WK   = (u16*)  (ws + off); off += (size_t)2048*1024*2;
  u16*   W1B  = (u16*)  (ws + off); off += (size_t)2048*1024*2;
  u16*   W2B  = (u16*)  (ws + off); off += (size_t)1024*2048*2;
  float* SA   = (float*)(ws + off); off += (size_t)BATCH*NCHUNK*1024*4;
  float* SB   = (float*)(ws + off); off += (size_t)BATCH*NCHUNK*1024*4;
  float* SA2  = (float*)(ws + off); off += (size_t)BATCH*NCHUNK*1024*4;
  float* SB2  = (float*)(ws + off); off += (size_t)BATCH*NCHUNK*1024*4;
  float* HP   = (float*)(ws + off); off += (size_t)BATCH*NCHUNK*1024*4;
  u16* ZB  = XB;   // z aliases x_bf16 (dead after GEMM1)
  u16* HID = RES;  // hid aliases res (dead after scan3_conv_k)
  u16* HF  = XB;   // GEMM3 bf16 output aliases z (dead after GEMM2)

  // allow 128 KiB dynamic LDS (idempotent host-side calls, graph-capture safe)
  hipFuncSetAttribute((const void*)gemm8p<0>, hipFuncAttributeMaxDynamicSharedMemorySize, 131072);
  hipFuncSetAttribute((const void*)gemm8p<1>, hipFuncAttributeMaxDynamicSharedMemorySize, 131072);
  hipFuncSetAttribute((const void*)gemm8p<2>, hipFuncAttributeMaxDynamicSharedMemorySize, 131072);

  // 1) fp32 -> bf16 converts (w_key row-permuted for interleaved res)
  cvt_bf16_k<<<(M_TOT*1024/4 + 255)/256, 256, 0, stream>>>(x,     XB,  M_TOT*1024/4);
  cvt_wkey_perm_k<<<(2048*1024/4 + 255)/256, 256, 0, stream>>>(w_key, WK);
  cvt_bf16_k<<<(2048*1024/4  + 255)/256, 256, 0, stream>>>(w1,    W1B, 2048*1024/4);
  cvt_bf16_k<<<(1024*2048/4  + 255)/256, 256, 0, stream>>>(w2,    W2B, 1024*2048/4);

  // 2) GEMM1 + activation epilogue -> res (bf16, theta/s interleaved)
  gemm8p<0><<<(M_TOT/256)*(2048/256), 512, 131072, stream>>>(XB, WK, nullptr, RES, M_TOT, 2048, 1024);

  // 3) chunked scan; stage3 fused with depthwise conv -> z (bf16)
  scan_stage1<<<BATCH*NCHUNK*2, 256, 0, stream>>>(RES, SA, SB, SA2, SB2);
  scan_stage2<<<16, 256, 0, stream>>>(SA, SB, HP);
  scan3_conv_k<<<BATCH*NCHUNK*2, 256, 0, stream>>>(RES, HP, SA2, SB2, conv_w, conv_b, ZB);

  // 5) GEMM2 + silu -> hid (bf16)
  gemm8p<1><<<(M_TOT/256)*(2048/256), 512, 131072, stream>>>(ZB, W1B, b1, HID, M_TOT, 2048, 1024);

  // 6) GEMM3 + bias -> h_final (bf16, into dead z buffer)
  gemm8p<2><<<(M_TOT/256)*(1024/256), 512, 131072, stream>>>(HID, W2B, b2, HF, M_TOT, 1024, 2048);

  // 7) RMSNorm: bf16 in -> fp32 out
  rmsnorm_bf_k<<<M_TOT, 256, 0, stream>>>(HF, out, norm_w);
}

// Round 12
// 298.165 us; speedup vs baseline: 1.1501x; 1.0658x over previous
//
#include <hip/hip_runtime.h>

typedef unsigned short u16;
typedef unsigned int u32;
typedef __attribute__((ext_vector_type(8))) short short8;  // 8 bf16 = 4 VGPR (MFMA A/B frag)
typedef __attribute__((ext_vector_type(4))) float f32x4;   // MFMA C/D frag

#define T_LEN 4096
#define BATCH 4
#define M_TOT (BATCH*T_LEN)   /* 16384 rows */
#define NCHUNK 64
#define CLEN 64               /* 4096/64 */

__device__ __forceinline__ u16 f2bf(float f){
  u32 u = __builtin_bit_cast(u32, f);
  u32 r = (u + 0x7FFFu + ((u >> 16) & 1u)) >> 16;   // RTN-even
  return (u16)r;
}
__device__ __forceinline__ float bf2f(u16 h){
  u32 u = ((u32)h) << 16; return __builtin_bit_cast(float, u);
}
__device__ __forceinline__ float sigmoid_(float v){ return 1.f/(1.f + __expf(-v)); }
__device__ __forceinline__ float tanh_pi_(float v){
  return 3.14159265358979323846f * (1.f - 2.f/(1.f + __expf(2.f*v)));
}

// ---------------- fp32 -> bf16 convert (vectorized x4) ----------------
__global__ __launch_bounds__(256) void cvt_bf16_k(const float* __restrict__ in,
                                                  u16* __restrict__ out, int n4){
  int g = blockIdx.x*256 + threadIdx.x;
  if (g >= n4) return;
  float4 v = reinterpret_cast<const float4*>(in)[g];
  reinterpret_cast<ushort4*>(out)[g] =
      make_ushort4(f2bf(v.x), f2bf(v.y), f2bf(v.z), f2bf(v.w));
}

// ---- merged weight convert: w_key|w1|w2 -> contiguous WK|W1B|W2B (1 launch) ----
#define WSEG 524288   /* 2048*1024/4 float4 per weight */
__global__ __launch_bounds__(256) void cvt_w_all_k(const float* __restrict__ wk,
                                                   const float* __restrict__ w1,
                                                   const float* __restrict__ w2,
                                                   u16* __restrict__ dst){
  int g = blockIdx.x*256 + threadIdx.x;           // 3*WSEG total
  const float* src; int loc;
  if (g < WSEG)        { src = wk; loc = g; }
  else if (g < 2*WSEG) { src = w1; loc = g - WSEG; }
  else                 { src = w2; loc = g - 2*WSEG; }
  float4 v = reinterpret_cast<const float4*>(src)[loc];
  reinterpret_cast<ushort4*>(dst)[g] =
      make_ushort4(f2bf(v.x), f2bf(v.y), f2bf(v.z), f2bf(v.w));
}

// ======= 256x256 8-phase bf16 GEMM (r6/r9 known-good core) =======
// C[M,N] = A[M,K] @ B[N,K]^T. 512 thr = 8 waves (2M x 4N), BK=64, LDS 128 KiB dyn.
// Phases by C-quadrant (mh,nh) x full K=64, JIT reads consumed same phase:
//   P0/P4 (0,0): 12 reads + lgkmcnt(8) | P1/P5 (0,1): 4 | P2/P6 (1,0): 8 | P3/P7: 0
// Stage map (2 gload_lds/phase):
//   P0: A1,A3(t+1) | P1: A0,A2(t+2) | P2: B0,B1(t+2) | P3: B2,B3(t+2) + VMCNT(6)
//   P4: A1,A3(t+2) | P5: A0,A2(t+3) | P6: B0,B1(t+3) | P7: B2,B3(t+3) + VMCNT(6)
// LDS swizzle: byte ^= (row&7)<<4 on reads; inverse-swizzled GLOBAL src on stages.
#define BAR() __builtin_amdgcn_s_barrier()
#define VMCNT(n) asm volatile("s_waitcnt vmcnt(" #n ")" ::: "memory")
#define LGKM0() asm volatile("s_waitcnt lgkmcnt(0)" ::: "memory")
#define LGKM8() asm volatile("s_waitcnt lgkmcnt(8)" ::: "memory")
#define FEN() asm volatile("" ::: "memory")
#define PRIO1() __builtin_amdgcn_s_setprio(1)
#define PRIO0() __builtin_amdgcn_s_setprio(0)

#define STAGE(buf, ab, q, kt) do { \
  const u16* _s = ((ab) ? Bb : Ab) + (size_t)(q)*rowK64 + (size_t)(kt)*64; \
  __builtin_amdgcn_global_load_lds( \
    (const __attribute__((address_space(1))) void*)_s, \
    (__attribute__((address_space(3))) void*)(smem + (buf)*65536 + (ab)*32768 + (q)*8192 + stb), \
    16, 0, 0); \
} while(0)

#define LDA(base, m, kk) (*(const short8*)((base) + (m)*2048 + ((kk) ? csw1 : csw0)))
#define LDB(base, n, kk) (*(const short8*)((base) + (n)*2048 + ((kk) ? csw1 : csw0)))

#define RD_A(base, h) do { _Pragma("unroll") \
  for (int ml=0; ml<4; ml++){ \
    aF[ml*2+0] = LDA(base, 4*(h)+ml, 0); \
    aF[ml*2+1] = LDA(base, 4*(h)+ml, 1); } } while(0)

#define RD_B(base, h) do { _Pragma("unroll") \
  for (int nl=0; nl<2; nl++){ \
    bF[(h)*4+nl*2+0] = LDB(base, 2*(h)+nl, 0); \
    bF[(h)*4+nl*2+1] = LDB(base, 2*(h)+nl, 1); } } while(0)

#define MFMAQ(mh, nh) do { _Pragma("unroll") \
  for (int kk=0; kk<2; kk++) \
  _Pragma("unroll") \
  for (int ml=0; ml<4; ml++) \
  _Pragma("unroll") \
  for (int nl=0; nl<2; nl++) \
    acc[4*(mh)+ml][2*(nh)+nl] = __builtin_amdgcn_mfma_f32_16x16x32_bf16( \
      aF[ml*2+kk], bF[(nh)*4+nl*2+kk], acc[4*(mh)+ml][2*(nh)+nl], 0,0,0); \
} while(0)

// EPI 0: GEMM1 -> bf16 activated res (col<1024: pi*tanh, else sigmoid; wave-uniform)
// EPI 1: GEMM2 -> bf16 silu(v + bias)
// EPI 2: GEMM3 -> bf16 v + bias (RMSNorm consumes bf16, writes fp32 out)
template<int EPI>
__global__ __launch_bounds__(512, 2) void gemm8p(
    const u16* __restrict__ Ag, const u16* __restrict__ Bg,
    const float* __restrict__ bias, void* __restrict__ Cout,
    int M, int N, int K)
{
  extern __shared__ __attribute__((aligned(16))) char smem[];
  const int tid = threadIdx.x;
  const int wid = tid >> 6, lane = tid & 63;
  const int wr = wid >> 2, wc = wid & 3;        // wave -> 128x64 output subtile
  const int fr = lane & 15, fq = lane >> 4;

  // T1: bijective XCD swizzle (nwg % 8 == 0 for all our launches)
  const int nbn = N >> 8;
  const int nwg = gridDim.x;
  const int bid = blockIdx.x;
  const int swzb = (bid & 7) * (nwg >> 3) + (bid >> 3);
  const int bm = swzb / nbn, bn = swzb - bm * nbn;

  const size_t rowK64 = (size_t)64 * K;
  // staging: thread t covers LDS bytes qbase + t*16 (linear); global source is
  // inverse-swizzled: row = t>>3 (within quarter), chunk = (t&7) ^ ((t>>3)&7)
  const u16* Ab = Ag + ((size_t)bm*256 + (tid>>3)) * K + ((tid & 7) ^ ((tid >> 3) & 7)) * 8;
  const u16* Bb = Bg + ((size_t)bn*256 + (tid>>3)) * K + ((tid & 7) ^ ((tid >> 3) & 7)) * 8;
  const u32 stb = (u32)(wid << 10);   // wave-uniform LDS staging base within quarter

  // swizzled ds_read addressing (row&7 == fr&7 since m*16 = 0 mod 8)
  const u32 csw0 = (u32)((fq*16)      ^ ((fr & 7) << 4));
  const u32 csw1 = (u32)((64 + fq*16) ^ ((fr & 7) << 4));
  const char* aB0 = smem +         (u32)(wr*128 + fr) * 128;
  const char* aB1 = aB0 + 65536;
  const char* bB0 = smem + 32768 + (u32)(wc*64  + fr) * 128;
  const char* bB1 = bB0 + 65536;

  f32x4 acc[8][4];
#pragma unroll
  for (int m=0;m<8;m++)
#pragma unroll
    for (int n=0;n<4;n++) acc[m][n] = f32x4{0.f,0.f,0.f,0.f};

  short8 aF[8];   // current quadrant-row A frags (m-half x 2kk)
  short8 bF[8];   // B frags, both n-halves x 2kk (live across the tile)

  const int NT = K >> 6;   // K-tiles (16 or 32)

  // prologue: tile0 all 8; tile1 A0,A2 + B all (6); gate retires tile0
  STAGE(0,0,0,0); STAGE(0,0,1,0); STAGE(0,0,2,0); STAGE(0,0,3,0);
  STAGE(0,1,0,0); STAGE(0,1,1,0); STAGE(0,1,2,0); STAGE(0,1,3,0);
  STAGE(1,0,0,1); STAGE(1,0,2,1);
  STAGE(1,1,0,1); STAGE(1,1,1,1); STAGE(1,1,2,1); STAGE(1,1,3,1);
  VMCNT(6);
  BAR();

  for (int i = 0; i < (NT>>1) - 1; ++i){
    const int tt = 2*i;
    // P0 (buf0, quad 0,0): 12 reads + lgkm8 pace
    RD_A(aB0,0); RD_B(bB0,0); FEN();
    STAGE(1,0,1,tt+1); STAGE(1,0,3,tt+1);
    LGKM8();
    BAR(); LGKM0();
    PRIO1(); MFMAQ(0,0); PRIO0();
    BAR();
    // P1 (0,1): 4 reads
    RD_B(bB0,1); FEN();
    STAGE(0,0,0,tt+2); STAGE(0,0,2,tt+2);
    BAR(); LGKM0();
    PRIO1(); MFMAQ(0,1); PRIO0();
    BAR();
    // P2 (1,0): 8 reads
    RD_A(aB0,1); FEN();
    STAGE(0,1,0,tt+2); STAGE(0,1,1,tt+2);
    BAR(); LGKM0();
    PRIO1(); MFMAQ(1,0); PRIO0();
    BAR();
    // P3 (1,1): 0 reads; gate tile t+1
    STAGE(0,1,2,tt+2); STAGE(0,1,3,tt+2);
    BAR();
    PRIO1(); MFMAQ(1,1); PRIO0();
    VMCNT(6);
    BAR();
    // P4 (buf1, quad 0,0)
    RD_A(aB1,0); RD_B(bB1,0); FEN();
    STAGE(0,0,1,tt+2); STAGE(0,0,3,tt+2);
    LGKM8();
    BAR(); LGKM0();
    PRIO1(); MFMAQ(0,0); PRIO0();
    BAR();
    // P5 (0,1)
    RD_B(bB1,1); FEN();
    STAGE(1,0,0,tt+3); STAGE(1,0,2,tt+3);
    BAR(); LGKM0();
    PRIO1(); MFMAQ(0,1); PRIO0();
    BAR();
    // P6 (1,0)
    RD_A(aB1,1); FEN();
    STAGE(1,1,0,tt+3); STAGE(1,1,1,tt+3);
    BAR(); LGKM0();
    PRIO1(); MFMAQ(1,0); PRIO0();
    BAR();
    // P7 (1,1): gate tile t+2
    STAGE(1,1,2,tt+3); STAGE(1,1,3,tt+3);
    BAR();
    PRIO1(); MFMAQ(1,1); PRIO0();
    VMCNT(6);
    BAR();
  }
  { // peeled final iteration: tiles NT-2 (buf0), NT-1 (buf1)
    RD_A(aB0,0); RD_B(bB0,0); FEN();
    STAGE(1,0,1,NT-1); STAGE(1,0,3,NT-1);
    LGKM8();
    BAR(); LGKM0();
    PRIO1(); MFMAQ(0,0); PRIO0();
    BAR();
    RD_B(bB0,1); FEN();
    BAR(); LGKM0();
    PRIO1(); MFMAQ(0,1); PRIO0();
    BAR();
    RD_A(aB0,1); FEN();
    BAR(); LGKM0();
    PRIO1(); MFMAQ(1,0); PRIO0();
    BAR();
    BAR();
    PRIO1(); MFMAQ(1,1); PRIO0();
    VMCNT(0);     // drain: tile NT-1 fully landed
    BAR();
    RD_A(aB1,0); RD_B(bB1,0); FEN();
    BAR(); LGKM0();
    PRIO1(); MFMAQ(0,0); PRIO0();
    BAR();
    RD_B(bB1,1); FEN();
    BAR(); LGKM0();
    PRIO1(); MFMAQ(0,1); PRIO0();
    BAR();
    RD_A(aB1,1); FEN();
    BAR(); LGKM0();
    PRIO1(); MFMAQ(1,0); PRIO0();
    BAR();
    PRIO1(); MFMAQ(1,1); PRIO0();
  }

  // epilogue: D reg r -> row = fq*4 + r, col = fr (m89-verified mapping)
  const int orow0 = bm*256 + wr*128;
  const int ocol0 = bn*256 + wc*64;
#pragma unroll
  for (int m=0;m<8;m++){
#pragma unroll
    for (int n=0;n<4;n++){
      const int col = ocol0 + n*16 + fr;
#pragma unroll
      for (int r=0;r<4;r++){
        const int row = orow0 + m*16 + fq*4 + r;
        float v = acc[m][n][r];
        if constexpr (EPI == 0){
          float o = (col < 1024) ? tanh_pi_(v) : sigmoid_(v);
          ((u16*)Cout)[(size_t)row*N + col] = f2bf(o);
        } else if constexpr (EPI == 1){
          v += bias[col];
          ((u16*)Cout)[(size_t)row*N + col] = f2bf(v * sigmoid_(v));
        } else {
          v += bias[col];
          ((u16*)Cout)[(size_t)row*N + col] = f2bf(v);
        }
      }
    }
  }
}

// ---------------- chunked lerp scan (res bf16, 2 channels/thread) ----------------
// res layout: [b][t][2048] bf16, col<1024 = theta' (pi*tanh), col>=1024 = s.
// recurrence: h_t = (1-s_t) h_{t-1} + s_t * theta'_t, h_{-1} = 0 (fp32 state)
__global__ __launch_bounds__(256) void scan_stage1(const u16* __restrict__ res,
                                                   float* __restrict__ sA,
                                                   float* __restrict__ sB,
                                                   float* __restrict__ sA2,
                                                   float* __restrict__ sB2){
  const int c0    = ((blockIdx.x & 1)*256 + threadIdx.x)*2;
  const int chunk = (blockIdx.x >> 1) & (NCHUNK-1);
  const int b     = blockIdx.x >> 7;
  const u16* p = res + ((size_t)(b*T_LEN + chunk*CLEN))*2048 + c0;
  float A0=1.f, B0v=0.f, A1=1.f, B1v=0.f;
#pragma unroll 4
  for (int t=0;t<CLEN-1;++t){
    ushort2 th = *reinterpret_cast<const ushort2*>(p);
    ushort2 sg = *reinterpret_cast<const ushort2*>(p+1024);
    float s0 = bf2f(sg.x), s1 = bf2f(sg.y);
    float a0 = 1.f - s0,   a1 = 1.f - s1;
    A0 *= a0;  B0v = a0*B0v + s0*bf2f(th.x);
    A1 *= a1;  B1v = a1*B1v + s1*bf2f(th.y);
    p += 2048;
  }
  const int idx = (b*NCHUNK + chunk)*1024 + c0;
  *reinterpret_cast<float2*>(&sA2[idx]) = make_float2(A0, A1);
  *reinterpret_cast<float2*>(&sB2[idx]) = make_float2(B0v, B1v);
  {
    ushort2 th = *reinterpret_cast<const ushort2*>(p);
    ushort2 sg = *reinterpret_cast<const ushort2*>(p+1024);
    float s0 = bf2f(sg.x), s1 = bf2f(sg.y);
    float a0 = 1.f - s0,   a1 = 1.f - s1;
    A0 *= a0;  B0v = a0*B0v + s0*bf2f(th.x);
    A1 *= a1;  B1v = a1*B1v + s1*bf2f(th.y);
  }
  *reinterpret_cast<float2*>(&sA[idx]) = make_float2(A0, A1);
  *reinterpret_cast<float2*>(&sB[idx]) = make_float2(B0v, B1v);
}

// 64 blocks x 64 threads: one wave per block, 4096 chains spread over 64 CUs
__global__ __launch_bounds__(64) void scan_stage2(const float* __restrict__ sA,
                                                  const float* __restrict__ sB,
                                                  float* __restrict__ Hp){
  const int g = blockIdx.x*64 + threadIdx.x;   // 4096 threads: b*1024+c
  const int b = g >> 10, c = g & 1023;
  float H = 0.f;
#pragma unroll
  for (int i=0;i<NCHUNK;++i){
    const int idx = (b*NCHUNK + i)*1024 + c;
    Hp[idx] = H;                 // state BEFORE chunk i
    H = sA[idx]*H + sB[idx];
  }
}

// ------- fused stage3 + depthwise causal conv(3) -> bf16 z (2 channels/thread) -------
__global__ __launch_bounds__(256) void scan3_conv_k(const u16* __restrict__ res,
                                                    const float* __restrict__ Hp,
                                                    const float* __restrict__ sA2,
                                                    const float* __restrict__ sB2,
                                                    const float* __restrict__ cw,
                                                    const float* __restrict__ cb,
                                                    u16* __restrict__ z){
  const int c0    = ((blockIdx.x & 1)*256 + threadIdx.x)*2;
  const int chunk = (blockIdx.x >> 1) & (NCHUNK-1);
  const int b     = blockIdx.x >> 7;
  const u16* p = res + ((size_t)(b*T_LEN + chunk*CLEN))*2048 + c0;
  u16*       q = z   + ((size_t)(b*T_LEN + chunk*CLEN))*1024 + c0;
  const int idx = (b*NCHUNK + chunk)*1024 + c0;
  float H0 = Hp[idx], H1 = Hp[idx+1];          // h[t0-1] (0 for chunk 0)
  float hm1_0 = H0, hm1_1 = H1;
  float hm2_0 = 0.f, hm2_1 = 0.f;
  if (chunk > 0){
    const int pidx = idx - 1024;
    hm2_0 = sA2[pidx]*Hp[pidx] + sB2[pidx];        // h[t0-2]
    hm2_1 = sA2[pidx+1]*Hp[pidx+1] + sB2[pidx+1];
  }
  const float w0_0 = cw[3*c0],   w1_0 = cw[3*c0+1], w2_0 = cw[3*c0+2], bb0 = cb[c0];
  const float w0_1 = cw[3*c0+3], w1_1 = cw[3*c0+4], w2_1 = cw[3*c0+5], bb1 = cb[c0+1];
#pragma unroll 4
  for (int t=0;t<CLEN;++t){
    ushort2 th = *reinterpret_cast<const ushort2*>(p);
    ushort2 sg = *reinterpret_cast<const ushort2*>(p+1024);
    float s0 = bf2f(sg.x), s1 = bf2f(sg.y);
    H0 = (1.f - s0)*H0 + s0*bf2f(th.x);
    H1 = (1.f - s1)*H1 + s1*bf2f(th.y);
    float v0 = H0 + bb0 + hm2_0*w0_0 + hm1_0*w1_0 + H0*w2_0;
    float v1 = H1 + bb1 + hm2_1*w0_1 + hm1_1*w1_1 + H1*w2_1;
    *reinterpret_cast<ushort2*>(q) = make_ushort2(f2bf(v0), f2bf(v1));
    hm2_0 = hm1_0; hm1_0 = H0;
    hm2_1 = hm1_1; hm1_1 = H1;
    p += 2048; q += 1024;
  }
}

// ------- row RMSNorm: bf16 in (h_final+bias), fp32 out; one block per row -------
__global__ __launch_bounds__(256) void rmsnorm_bf_k(const u16* __restrict__ in,
                                                    float* __restrict__ out,
                                                    const float* __restrict__ w){
  const int row = blockIdx.x;
  const int tid = threadIdx.x;
  const u16* p = in + (size_t)row*1024 + tid*4;
  ushort4 v4 = *reinterpret_cast<const ushort4*>(p);
  float a = bf2f(v4.x), b = bf2f(v4.y), c = bf2f(v4.z), d = bf2f(v4.w);
  float ss = a*a + b*b + c*c + d*d;
#pragma unroll
  for (int o=32; o>0; o>>=1) ss += __shfl_xor(ss, o, 64);
  __shared__ float red[4];
  if ((tid & 63) == 0) red[tid >> 6] = ss;
  __syncthreads();
  float tot = red[0] + red[1] + red[2] + red[3];
  float scale = rsqrtf(tot * (1.f/1024.f) + 1e-6f);
  float4 wv = reinterpret_cast<const float4*>(w)[tid];
  float4 o;
  o.x = a*scale*wv.x; o.y = b*scale*wv.y;
  o.z = c*scale*wv.z; o.w = d*scale*wv.w;
  reinterpret_cast<float4*>(out + (size_t)row*1024)[tid] = o;
}

extern "C" void kernel_launch(void* const* d_in, const int* in_sizes, int n_in,
                              void* d_out, int out_size, void* d_ws, size_t ws_size,
                              hipStream_t stream) {
  const float* x      = (const float*)d_in[0];
  const float* w_key  = (const float*)d_in[1];
  const float* conv_w = (const float*)d_in[2];
  const float* conv_b = (const float*)d_in[3];
  const float* w1     = (const float*)d_in[4];
  const float* b1     = (const float*)d_in[5];
  const float* w2     = (const float*)d_in[6];
  const float* b2     = (const float*)d_in[7];
  const float* norm_w = (const float*)d_in[8];
  float* out = (float*)d_out;
  char*  ws  = (char*)d_ws;

  // workspace layout (~120 MB); WK|W1B|W2B contiguous for merged convert
  size_t off = 0;
  u16*   RES  = (u16*)  (ws + off); off += (size_t)M_TOT*2048*2; // bf16 res; reused as hid
  u16*   XB   = (u16*)  (ws + off); off += (size_t)M_TOT*1024*2; // x bf16; reused as z, then h_final
  u16*   WK   = (u16*)  (ws + off); off += (size_t)2048*1024*2;
  u16*   W1B  = (u16*)  (ws + off); off += (size_t)2048*1024*2;
  u16*   W2B  = (u16*)  (ws + off); off += (size_t)1024*2048*2;
  float* SA   = (float*)(ws + off); off += (size_t)BATCH*NCHUNK*1024*4;
  float* SB   = (float*)(ws + off); off += (size_t)BATCH*NCHUNK*1024*4;
  float* SA2  = (float*)(ws + off); off += (size_t)BATCH*NCHUNK*1024*4;
  float* SB2  = (float*)(ws + off); off += (size_t)BATCH*NCHUNK*1024*4;
  float* HP   = (float*)(ws + off); off += (size_t)BATCH*NCHUNK*1024*4;
  u16* ZB  = XB;   // z aliases x_bf16 (dead after GEMM1)
  u16* HID = RES;  // hid aliases res (dead after scan3_conv_k)
  u16* HF  = XB;   // GEMM3 bf16 output aliases z (dead after GEMM2)

  // allow 128 KiB dynamic LDS (idempotent host-side calls, graph-capture safe)
  hipFuncSetAttribute((const void*)gemm8p<0>, hipFuncAttributeMaxDynamicSharedMemorySize, 131072);
  hipFuncSetAttribute((const void*)gemm8p<1>, hipFuncAttributeMaxDynamicSharedMemorySize, 131072);
  hipFuncSetAttribute((const void*)gemm8p<2>, hipFuncAttributeMaxDynamicSharedMemorySize, 131072);

  // 1) fp32 -> bf16 converts (weights merged into one launch)
  cvt_bf16_k<<<(M_TOT*1024/4 + 255)/256, 256, 0, stream>>>(x, XB, M_TOT*1024/4);
  cvt_w_all_k<<<(3*WSEG + 255)/256, 256, 0, stream>>>(w_key, w1, w2, WK);

  // 2) GEMM1 + activation epilogue -> res (bf16)
  gemm8p<0><<<(M_TOT/256)*(2048/256), 512, 131072, stream>>>(XB, WK, nullptr, RES, M_TOT, 2048, 1024);

  // 3) chunked scan; stage3 fused with depthwise conv -> z (bf16)
  scan_stage1<<<BATCH*NCHUNK*2, 256, 0, stream>>>(RES, SA, SB, SA2, SB2);
  scan_stage2<<<64, 64, 0, stream>>>(SA, SB, HP);
  scan3_conv_k<<<BATCH*NCHUNK*2, 256, 0, stream>>>(RES, HP, SA2, SB2, conv_w, conv_b, ZB);

  // 5) GEMM2 + silu -> hid (bf16)
  gemm8p<1><<<(M_TOT/256)*(2048/256), 512, 131072, stream>>>(ZB, W1B, b1, HID, M_TOT, 2048, 1024);

  // 6) GEMM3 + bias -> h_final (bf16, into dead z buffer)
  gemm8p<2><<<(M_TOT/256)*(1024/256), 512, 131072, stream>>>(HID, W2B, b2, HF, M_TOT, 1024, 2048);

  // 7) RMSNorm: bf16 in -> fp32 out
  rmsnorm_bf_k<<<M_TOT, 256, 0, stream>>>(HF, out, norm_w);
}